// Round 14
// baseline (476.489 us; speedup 1.0000x reference)
//
#include <hip/hip_runtime.h>
#include <hip/hip_bf16.h>

// x [B=2, C=16, T=31, H=256, W=256] fp32
#define TDIM 31
#define TS   65536                 // t stride (H*W)
#define CS   (TDIM * TS)           // c stride = 2,031,616
#define BS   (16 * CS)             // b stride
#define NTOT (2 * BS)              // 65,011,712
#define GAP_INV (1.0f / (31.0f * 65536.0f))

typedef __attribute__((ext_vector_type(8))) unsigned short ushort8v;
typedef float __attribute__((ext_vector_type(2))) f32x2;

__device__ __forceinline__ float frcp(float v){ return __builtin_amdgcn_rcpf(v); }
__device__ __forceinline__ float fexp2_(float v){ return __builtin_amdgcn_exp2f(v); }
__device__ __forceinline__ float ftanh(float x){ float e = fexp2_(x*2.8853900817779268f); return 1.0f - 2.0f*frcp(e+1.0f); }
__device__ __forceinline__ float fsigm(float x){ float e = fexp2_(x*-1.4426950408889634f); return frcp(1.0f+e); }
__device__ __forceinline__ unsigned rhu16(float x){ return (__float_as_uint(x) + 0x8000u) >> 16; }
__device__ __forceinline__ float bf2f(unsigned b){ return __uint_as_float(b << 16); }

// ---------------- kA: gates (pure streaming, t-parallel, 2 voxels/thread) ----
// r9 (1 voxel, scalar FMA): 218us @ VALUBusy 86% -> issue-bound.
// r12 (1 voxel, pk_fma):    234us @ VALUBusy 62% -> latency-exposed.
// Fix: 2 voxels per thread (pos, pos+32768). Weight LDS reads amortize 2x and
// widen to b128; 4 independent pk_fma chains per o cover LDS/HBM latency.
// Exact fp32 FMA via __builtin_elementwise_fma (NO inline asm). Writes packed
// (z snorm16 | f unorm16) u32 into gates (= d_out scratch; k3 overwrites).
__global__ __launch_bounds__(256) void kA_gates(
    const float* __restrict__ x,
    const float* __restrict__ wf1, const float* __restrict__ bf1,
    const float* __restrict__ wf2, const float* __restrict__ bf2,
    const float* __restrict__ ww1, const float* __restrict__ bw1,
    const float* __restrict__ ww2, const float* __restrict__ bw2,
    unsigned int* __restrict__ gates)
{
    __shared__ __align__(16) float sW[4][256];   // wf1, ww1, wf2, ww2 ([o][c])
    __shared__ float sB[4][16];

    const int tid = threadIdx.x;
    sW[0][tid] = wf1[tid]; sW[1][tid] = ww1[tid];
    sW[2][tid] = wf2[tid]; sW[3][tid] = ww2[tid];
    if (tid < 16) {
        sB[0][tid] = bf1[tid]; sB[1][tid] = bw1[tid];
        sB[2][tid] = bf2[tid]; sB[3][tid] = bw2[tid];
    }
    __syncthreads();

    const int pos = blockIdx.x * 256 + tid;     // 0..32767
    const int t   = blockIdx.y;                 // 0..30
    const int b   = blockIdx.z;                 // 0..1
    const unsigned baseA = (unsigned)b * BS + (unsigned)t * TS + (unsigned)pos;
    const unsigned baseB = baseA + 32768u;

    f32x2 xA[8], xB[8];
#pragma unroll
    for (int q = 0; q < 8; ++q) {
        xA[q].x = x[baseA + (unsigned)(2*q)   * CS];
        xA[q].y = x[baseA + (unsigned)(2*q+1) * CS];
        xB[q].x = x[baseB + (unsigned)(2*q)   * CS];
        xB[q].y = x[baseB + (unsigned)(2*q+1) * CS];
    }

    // conv1 (both branches, both voxels) + tanh
    f32x2 afA[8], awA[8], afB[8], awB[8];
#pragma unroll
    for (int o = 0; o < 16; ++o) {
        f32x2 a1A = {sB[0][o], 0.f}, a2A = {sB[1][o], 0.f};
        f32x2 a1B = a1A, a2B = a2A;
#pragma unroll
        for (int j = 0; j < 4; ++j) {
            const float4 w1 = *(const float4*)&sW[0][o * 16 + j * 4];
            const float4 w2 = *(const float4*)&sW[1][o * 16 + j * 4];
            const f32x2 w1lo = {w1.x, w1.y}, w1hi = {w1.z, w1.w};
            const f32x2 w2lo = {w2.x, w2.y}, w2hi = {w2.z, w2.w};
            a1A = __builtin_elementwise_fma(w1lo, xA[2*j],   a1A);
            a1A = __builtin_elementwise_fma(w1hi, xA[2*j+1], a1A);
            a2A = __builtin_elementwise_fma(w2lo, xA[2*j],   a2A);
            a2A = __builtin_elementwise_fma(w2hi, xA[2*j+1], a2A);
            a1B = __builtin_elementwise_fma(w1lo, xB[2*j],   a1B);
            a1B = __builtin_elementwise_fma(w1hi, xB[2*j+1], a1B);
            a2B = __builtin_elementwise_fma(w2lo, xB[2*j],   a2B);
            a2B = __builtin_elementwise_fma(w2hi, xB[2*j+1], a2B);
        }
        const float vA = ftanh(a1A.x + a1A.y), wA = ftanh(a2A.x + a2A.y);
        const float vB = ftanh(a1B.x + a1B.y), wB = ftanh(a2B.x + a2B.y);
        if (o & 1) { afA[o>>1].y = vA; awA[o>>1].y = wA; afB[o>>1].y = vB; awB[o>>1].y = wB; }
        else       { afA[o>>1].x = vA; awA[o>>1].x = wA; afB[o>>1].x = vB; awB[o>>1].x = wB; }
    }
    // conv2 (both branches, both voxels) -> z=tanh, f=sigm -> pack -> store
#pragma unroll
    for (int o = 0; o < 16; ++o) {
        f32x2 a1A = {sB[2][o], 0.f}, a2A = {sB[3][o], 0.f};
        f32x2 a1B = a1A, a2B = a2A;
#pragma unroll
        for (int j = 0; j < 4; ++j) {
            const float4 w1 = *(const float4*)&sW[2][o * 16 + j * 4];
            const float4 w2 = *(const float4*)&sW[3][o * 16 + j * 4];
            const f32x2 w1lo = {w1.x, w1.y}, w1hi = {w1.z, w1.w};
            const f32x2 w2lo = {w2.x, w2.y}, w2hi = {w2.z, w2.w};
            a1A = __builtin_elementwise_fma(w1lo, afA[2*j],   a1A);
            a1A = __builtin_elementwise_fma(w1hi, afA[2*j+1], a1A);
            a2A = __builtin_elementwise_fma(w2lo, awA[2*j],   a2A);
            a2A = __builtin_elementwise_fma(w2hi, awA[2*j+1], a2A);
            a1B = __builtin_elementwise_fma(w1lo, afB[2*j],   a1B);
            a1B = __builtin_elementwise_fma(w1hi, afB[2*j+1], a1B);
            a2B = __builtin_elementwise_fma(w2lo, awB[2*j],   a2B);
            a2B = __builtin_elementwise_fma(w2hi, awB[2*j+1], a2B);
        }
        {
            const float z = ftanh(a1A.x + a1A.y);
            const float f = fsigm(a2A.x + a2A.y);
            const int zi = (int)__builtin_rintf(z * 32767.0f);
            const unsigned fu = (unsigned)(f * 65535.0f + 0.5f);
            gates[baseA + (unsigned)o * CS] = ((unsigned)zi << 16) | (fu & 0xFFFFu);
        }
        {
            const float z = ftanh(a1B.x + a1B.y);
            const float f = fsigm(a2B.x + a2B.y);
            const int zi = (int)__builtin_rintf(z * 32767.0f);
            const unsigned fu = (unsigned)(f * 65535.0f + 0.5f);
            gates[baseB + (unsigned)o * CS] = ((unsigned)zi << 16) | (fu & 0xFFFFu);
        }
    }
}

// ---------------- kB: scan over t (pure streaming) ----------------
template<bool BF16H>
__global__ __launch_bounds__(256) void kB_scan(
    unsigned int* __restrict__ gates,       // also f32 h output when !BF16H
    unsigned short* __restrict__ hb,
    float* __restrict__ partials)
{
    const int pos = blockIdx.x * 256 + threadIdx.x;   // 0..65535
    const int c   = blockIdx.y;                       // 0..15
    const int b   = blockIdx.z;                       // 0..1
    const unsigned base = (unsigned)b * BS + (unsigned)c * CS + (unsigned)pos;

    float h = 0.f, s = 0.f;
#pragma unroll
    for (int t = 0; t < TDIM; ++t) {
        const unsigned wd = gates[base + (unsigned)t * TS];
        const float z = (float)((int)wd >> 16) * (1.0f / 32767.0f);
        const float f = (float)(wd & 0xFFFFu) * (1.0f / 65535.0f);
        h = fmaf(f, h - z, z);              // f*h + (1-f)*z
        s += h;
        if (BF16H) hb[base + (unsigned)t * TS] = (unsigned short)rhu16(h);
        else       ((float*)gates)[base + (unsigned)t * TS] = h;   // in-place
    }
#pragma unroll
    for (int off = 32; off; off >>= 1) s += __shfl_down(s, off, 64);
    const int lane = threadIdx.x & 63, wv = threadIdx.x >> 6;
    if (lane == 0)
        partials[(unsigned)(b * 16 + c) * 1024 + blockIdx.x * 4 + wv] = s;
}

// ---------------- k2: reduce partials -> att ----------------
__global__ __launch_bounds__(1024) void k2_attention(
    const float* __restrict__ partials, const float* __restrict__ wsca,
    const float* __restrict__ bsca, float* __restrict__ att)
{
    __shared__ float red[32][32];
    __shared__ float gap[32];
    const int tid = threadIdx.x;
    {
        const int bc = tid >> 5, seg = tid & 31;
        float s = 0.f;
        const float* p = partials + (unsigned)bc * 1024 + seg * 32;
#pragma unroll
        for (int j = 0; j < 32; ++j) s += p[j];
        red[bc][seg] = s;
    }
    __syncthreads();
    if (tid < 32) {
        float s = 0.f;
#pragma unroll
        for (int g = 0; g < 32; ++g) s += red[tid][g];
        gap[tid] = s * GAP_INV;
    }
    __syncthreads();
    if (tid < 32) {
        const int b = tid >> 4, o = tid & 15;
        float acc = bsca[o];
#pragma unroll
        for (int c = 0; c < 16; ++c) acc = fmaf(wsca[o*16 + c], gap[b*16 + c], acc);
        att[b*16 + o] = fsigm(acc);
    }
}

// ---------------- k3: scale ----------------
__global__ __launch_bounds__(1024) void k3_scale_b(
    const unsigned short* __restrict__ hb, const float* __restrict__ att,
    float* __restrict__ out)
{
    const int bc = blockIdx.y;
    const float a = att[bc];
    const unsigned i = blockIdx.x * 1024 + threadIdx.x;     // < 253,952 = CS/8
    const size_t base = (size_t)bc * CS;
    const ushort8v v = ((const ushort8v*)(hb + base))[i];
    float4 o1, o2;
    o1.x = bf2f(v[0])*a; o1.y = bf2f(v[1])*a; o1.z = bf2f(v[2])*a; o1.w = bf2f(v[3])*a;
    o2.x = bf2f(v[4])*a; o2.y = bf2f(v[5])*a; o2.z = bf2f(v[6])*a; o2.w = bf2f(v[7])*a;
    float4* op = (float4*)(out + base);
    op[i*2]     = o1;
    op[i*2 + 1] = o2;
}

__global__ __launch_bounds__(1024) void k3_scale_a(
    const float* __restrict__ att, float* __restrict__ out)
{
    const int bc = blockIdx.y;
    const float a = att[bc];
    const unsigned i = blockIdx.x * 1024 + threadIdx.x;
    float4* op = (float4*)(out + (size_t)bc * CS);
    float4 v1 = op[i*2], v2 = op[i*2 + 1];
    v1.x *= a; v1.y *= a; v1.z *= a; v1.w *= a;
    v2.x *= a; v2.y *= a; v2.z *= a; v2.w *= a;
    op[i*2] = v1; op[i*2 + 1] = v2;
}

extern "C" void kernel_launch(void* const* d_in, const int* in_sizes, int n_in,
                              void* d_out, int out_size, void* d_ws, size_t ws_size,
                              hipStream_t stream) {
    const float* x    = (const float*)d_in[0];
    const float* wf1  = (const float*)d_in[1];
    const float* bf1  = (const float*)d_in[2];
    const float* wf2  = (const float*)d_in[3];
    const float* bf2  = (const float*)d_in[4];
    const float* ww1  = (const float*)d_in[5];
    const float* bw1  = (const float*)d_in[6];
    const float* ww2  = (const float*)d_in[7];
    const float* bw2  = (const float*)d_in[8];
    const float* wsca = (const float*)d_in[9];
    const float* bsca = (const float*)d_in[10];
    float* out = (float*)d_out;

    const size_t hbBytes   = (size_t)NTOT * 2;               // 130,023,424
    const size_t partBytes = (size_t)32 * 1024 * 4;          // 131,072
    const bool bf16h = ws_size >= hbBytes + partBytes + 256;

    // d_out doubles as the gate buffer (u32 per element = exactly out_size);
    // kB consumes gates (fallback: overwrites them with f32 h); k3 then fully
    // overwrites d_out with the final scaled output.
    unsigned int* gates = (unsigned int*)d_out;
    unsigned short* hb = (unsigned short*)d_ws;
    float* partials = bf16h ? (float*)((char*)d_ws + hbBytes) : (float*)d_ws;
    float* att = partials + 32 * 1024;

    kA_gates<<<dim3(128, TDIM, 2), 256, 0, stream>>>(
        x, wf1, bf1, wf2, bf2, ww1, bw1, ww2, bw2, gates);

    if (bf16h) {
        kB_scan<true><<<dim3(256, 16, 2), 256, 0, stream>>>(gates, hb, partials);
        k2_attention<<<1, 1024, 0, stream>>>(partials, wsca, bsca, att);
        k3_scale_b<<<dim3(248, 32), 1024, 0, stream>>>(hb, att, out);
    } else {
        kB_scan<false><<<dim3(256, 16, 2), 256, 0, stream>>>(gates, hb, partials);
        k2_attention<<<1, 1024, 0, stream>>>(partials, wsca, bsca, att);
        k3_scale_a<<<dim3(248, 32), 1024, 0, stream>>>(att, out);
    }
}

// Round 15
// 314.879 us; speedup vs baseline: 1.5132x; 1.5132x over previous
//
#include <hip/hip_runtime.h>
#include <hip/hip_bf16.h>

// x [B=2, C=16, T=31, H=256, W=256] fp32
#define TDIM 31
#define TS   65536                 // t stride (H*W)
#define CS   (TDIM * TS)           // c stride = 2,031,616
#define BS   (16 * CS)             // b stride
#define NTOT (2 * BS)              // 65,011,712
#define GAP_INV (1.0f / (31.0f * 65536.0f))

typedef __attribute__((ext_vector_type(8))) unsigned short ushort8v;

__device__ __forceinline__ float frcp(float v){ return __builtin_amdgcn_rcpf(v); }
__device__ __forceinline__ float fexp2_(float v){ return __builtin_amdgcn_exp2f(v); }
__device__ __forceinline__ float ftanh(float x){ float e = fexp2_(x*2.8853900817779268f); return 1.0f - 2.0f*frcp(e+1.0f); }
__device__ __forceinline__ float fsigm(float x){ float e = fexp2_(x*-1.4426950408889634f); return frcp(1.0f+e); }
__device__ __forceinline__ unsigned rhu16(float x){ return (__float_as_uint(x) + 0x8000u) >> 16; }
__device__ __forceinline__ float bf2f(unsigned b){ return __uint_as_float(b << 16); }

// ---------------- kA: gates (pure streaming, t-parallel) ----------------
// r9 structure (218us, VALUBusy 86%) but weights read DIRECTLY from global
// with compile-time indices: every weight access is wave-uniform -> compiler
// emits s_load (SGPR base + imm) and v_fma with SGPR operand. This removes
// the 256 ds_read_b128/voxel that r9's LDS staging cost (~12cy each = the
// hidden 2.4x over the pure FMA count). Scalar pipe issues parallel to VALU;
// 4KB weight region stays hot in scalar cache. NO LDS at all.
// r13 lesson: do NOT buy ILP with VGPRs (156 VGPR -> 11% occ). 1 voxel/thread.
// Thread = one (b, t, pos); writes packed (z snorm16 | f unorm16) u32 into
// gates (= d_out scratch; k3 overwrites d_out afterwards).
__global__ __launch_bounds__(256) void kA_gates(
    const float* __restrict__ x,
    const float* __restrict__ wf1, const float* __restrict__ bf1,
    const float* __restrict__ wf2, const float* __restrict__ bf2,
    const float* __restrict__ ww1, const float* __restrict__ bw1,
    const float* __restrict__ ww2, const float* __restrict__ bw2,
    unsigned int* __restrict__ gates)
{
    const int tid = threadIdx.x;
    const int pos = blockIdx.x * 256 + tid;     // 0..65535
    const int t   = blockIdx.y;                 // 0..30
    const int b   = blockIdx.z;                 // 0..1
    const unsigned base = (unsigned)b * BS + (unsigned)t * TS + (unsigned)pos;

    float xv[16];
#pragma unroll
    for (int c = 0; c < 16; ++c) xv[c] = x[base + (unsigned)c * CS];

    // conv1 (both branches) + tanh -- all weight indices compile-time constant
    float af[16], aw[16];
#pragma unroll
    for (int o = 0; o < 16; ++o) {
        float a1 = bf1[o], a2 = bw1[o];
#pragma unroll
        for (int c = 0; c < 16; ++c) {
            a1 = fmaf(wf1[o * 16 + c], xv[c], a1);
            a2 = fmaf(ww1[o * 16 + c], xv[c], a2);
        }
        af[o] = ftanh(a1);
        aw[o] = ftanh(a2);
    }
    // conv2 (both branches) -> z=tanh, f=sigm -> pack -> store
#pragma unroll
    for (int o = 0; o < 16; ++o) {
        float a1 = bf2[o], a2 = bw2[o];
#pragma unroll
        for (int c = 0; c < 16; ++c) {
            a1 = fmaf(wf2[o * 16 + c], af[c], a1);
            a2 = fmaf(ww2[o * 16 + c], aw[c], a2);
        }
        const float z = ftanh(a1);
        const float f = fsigm(a2);
        const int zi = (int)__builtin_rintf(z * 32767.0f);
        const unsigned fu = (unsigned)(f * 65535.0f + 0.5f);
        gates[base + (unsigned)o * CS] = ((unsigned)zi << 16) | (fu & 0xFFFFu);
    }
}

// ---------------- kB: scan over t (pure streaming) ----------------
// Thread = one (b, c, pos). 31 independent stride-TS gate loads (pipelined),
// register h-chain, h stored bf16 to ws (or f32 in-place over gates when ws
// is too small). Wave-level GAP partial per (b,c).
template<bool BF16H>
__global__ __launch_bounds__(256) void kB_scan(
    unsigned int* __restrict__ gates,       // also f32 h output when !BF16H
    unsigned short* __restrict__ hb,
    float* __restrict__ partials)
{
    const int pos = blockIdx.x * 256 + threadIdx.x;   // 0..65535
    const int c   = blockIdx.y;                       // 0..15
    const int b   = blockIdx.z;                       // 0..1
    const unsigned base = (unsigned)b * BS + (unsigned)c * CS + (unsigned)pos;

    float h = 0.f, s = 0.f;
#pragma unroll
    for (int t = 0; t < TDIM; ++t) {
        const unsigned wd = gates[base + (unsigned)t * TS];
        const float z = (float)((int)wd >> 16) * (1.0f / 32767.0f);
        const float f = (float)(wd & 0xFFFFu) * (1.0f / 65535.0f);
        h = fmaf(f, h - z, z);              // f*h + (1-f)*z
        s += h;
        if (BF16H) hb[base + (unsigned)t * TS] = (unsigned short)rhu16(h);
        else       ((float*)gates)[base + (unsigned)t * TS] = h;   // in-place
    }
#pragma unroll
    for (int off = 32; off; off >>= 1) s += __shfl_down(s, off, 64);
    const int lane = threadIdx.x & 63, wv = threadIdx.x >> 6;
    if (lane == 0)
        partials[(unsigned)(b * 16 + c) * 1024 + blockIdx.x * 4 + wv] = s;
}

// ---------------- k2: reduce partials -> att ----------------
__global__ __launch_bounds__(1024) void k2_attention(
    const float* __restrict__ partials, const float* __restrict__ wsca,
    const float* __restrict__ bsca, float* __restrict__ att)
{
    __shared__ float red[32][32];
    __shared__ float gap[32];
    const int tid = threadIdx.x;
    {
        const int bc = tid >> 5, seg = tid & 31;
        float s = 0.f;
        const float* p = partials + (unsigned)bc * 1024 + seg * 32;
#pragma unroll
        for (int j = 0; j < 32; ++j) s += p[j];
        red[bc][seg] = s;
    }
    __syncthreads();
    if (tid < 32) {
        float s = 0.f;
#pragma unroll
        for (int g = 0; g < 32; ++g) s += red[tid][g];
        gap[tid] = s * GAP_INV;
    }
    __syncthreads();
    if (tid < 32) {
        const int b = tid >> 4, o = tid & 15;
        float acc = bsca[o];
#pragma unroll
        for (int c = 0; c < 16; ++c) acc = fmaf(wsca[o*16 + c], gap[b*16 + c], acc);
        att[b*16 + o] = fsigm(acc);
    }
}

// ---------------- k3: scale ----------------
// bf16-h path: read h (bf16, ws), write fp32 out. grid (248, 32) x 1024: exact.
__global__ __launch_bounds__(1024) void k3_scale_b(
    const unsigned short* __restrict__ hb, const float* __restrict__ att,
    float* __restrict__ out)
{
    const int bc = blockIdx.y;
    const float a = att[bc];
    const unsigned i = blockIdx.x * 1024 + threadIdx.x;     // < 253,952 = CS/8
    const size_t base = (size_t)bc * CS;
    const ushort8v v = ((const ushort8v*)(hb + base))[i];
    float4 o1, o2;
    o1.x = bf2f(v[0])*a; o1.y = bf2f(v[1])*a; o1.z = bf2f(v[2])*a; o1.w = bf2f(v[3])*a;
    o2.x = bf2f(v[4])*a; o2.y = bf2f(v[5])*a; o2.z = bf2f(v[6])*a; o2.w = bf2f(v[7])*a;
    float4* op = (float4*)(out + base);
    op[i*2]     = o1;
    op[i*2 + 1] = o2;
}

// fallback: in-place fp32 scale (h already resides in d_out)
__global__ __launch_bounds__(1024) void k3_scale_a(
    const float* __restrict__ att, float* __restrict__ out)
{
    const int bc = blockIdx.y;
    const float a = att[bc];
    const unsigned i = blockIdx.x * 1024 + threadIdx.x;
    float4* op = (float4*)(out + (size_t)bc * CS);
    float4 v1 = op[i*2], v2 = op[i*2 + 1];
    v1.x *= a; v1.y *= a; v1.z *= a; v1.w *= a;
    v2.x *= a; v2.y *= a; v2.z *= a; v2.w *= a;
    op[i*2] = v1; op[i*2 + 1] = v2;
}

extern "C" void kernel_launch(void* const* d_in, const int* in_sizes, int n_in,
                              void* d_out, int out_size, void* d_ws, size_t ws_size,
                              hipStream_t stream) {
    const float* x    = (const float*)d_in[0];
    const float* wf1  = (const float*)d_in[1];
    const float* bf1  = (const float*)d_in[2];
    const float* wf2  = (const float*)d_in[3];
    const float* bf2  = (const float*)d_in[4];
    const float* ww1  = (const float*)d_in[5];
    const float* bw1  = (const float*)d_in[6];
    const float* ww2  = (const float*)d_in[7];
    const float* bw2  = (const float*)d_in[8];
    const float* wsca = (const float*)d_in[9];
    const float* bsca = (const float*)d_in[10];
    float* out = (float*)d_out;

    const size_t hbBytes   = (size_t)NTOT * 2;               // 130,023,424
    const size_t partBytes = (size_t)32 * 1024 * 4;          // 131,072
    const bool bf16h = ws_size >= hbBytes + partBytes + 256;

    // d_out doubles as the gate buffer (u32 per element = exactly out_size);
    // kB consumes gates (fallback: overwrites them with f32 h); k3 then fully
    // overwrites d_out with the final scaled output.
    unsigned int* gates = (unsigned int*)d_out;
    unsigned short* hb = (unsigned short*)d_ws;
    float* partials = bf16h ? (float*)((char*)d_ws + hbBytes) : (float*)d_ws;
    float* att = partials + 32 * 1024;

    kA_gates<<<dim3(256, TDIM, 2), 256, 0, stream>>>(
        x, wf1, bf1, wf2, bf2, ww1, bw1, ww2, bw2, gates);

    if (bf16h) {
        kB_scan<true><<<dim3(256, 16, 2), 256, 0, stream>>>(gates, hb, partials);
        k2_attention<<<1, 1024, 0, stream>>>(partials, wsca, bsca, att);
        k3_scale_b<<<dim3(248, 32), 1024, 0, stream>>>(hb, att, out);
    } else {
        kB_scan<false><<<dim3(256, 16, 2), 256, 0, stream>>>(gates, hb, partials);
        k2_attention<<<1, 1024, 0, stream>>>(partials, wsca, bsca, att);
        k3_scale_a<<<dim3(248, 32), 1024, 0, stream>>>(att, out);
    }
}

// Round 16
// 306.683 us; speedup vs baseline: 1.5537x; 1.0267x over previous
//
#include <hip/hip_runtime.h>
#include <hip/hip_bf16.h>

// x [B=2, C=16, T=31, H=256, W=256] fp32
#define TDIM 31
#define TS   65536                 // t stride (H*W)
#define CS   (TDIM * TS)           // c stride = 2,031,616
#define BS   (16 * CS)             // b stride
#define NTOT (2 * BS)              // 65,011,712
#define GAP_INV (1.0f / (31.0f * 65536.0f))

typedef __attribute__((ext_vector_type(8))) unsigned short ushort8v;
typedef float __attribute__((ext_vector_type(2))) f32x2;

__device__ __forceinline__ float frcp(float v){ return __builtin_amdgcn_rcpf(v); }
__device__ __forceinline__ float fexp2_(float v){ return __builtin_amdgcn_exp2f(v); }
__device__ __forceinline__ float ftanh(float x){ float e = fexp2_(x*2.8853900817779268f); return 1.0f - 2.0f*frcp(e+1.0f); }
__device__ __forceinline__ float fsigm(float x){ float e = fexp2_(x*-1.4426950408889634f); return frcp(1.0f+e); }
__device__ __forceinline__ unsigned rhu16(float x){ return (__float_as_uint(x) + 0x8000u) >> 16; }
__device__ __forceinline__ float bf2f(unsigned b){ return __uint_as_float(b << 16); }

// ---------------- kA: gates (pure streaming, t-parallel) ----------------
// r14 (scalar FMA, SGPR weights, no LDS): 201us @ VALUBusy 93% -> issue-bound.
// r15: halve FMA issues with v_pk_fma_f32. Weight PAIRS read directly from
// global at compile-time indices -> s_load_dwordx2 (scalar pipe, parallel to
// VALU) + pk_fma with SGPR-pair operand. r12's pk_fma regression was at 33%
// occupancy with per-use LDS reads; both conditions are gone here (63% occ,
// scalar-cache weights). Exact fp32 FMA via __builtin_elementwise_fma --
// NO inline asm (r10 lesson). 1 voxel/thread (r13 lesson: don't buy ILP with
// VGPRs). Writes packed (z snorm16 | f unorm16) u32 into gates (= d_out
// scratch; k3 overwrites d_out afterwards).
__global__ __launch_bounds__(256) void kA_gates(
    const float* __restrict__ x,
    const float* __restrict__ wf1, const float* __restrict__ bf1,
    const float* __restrict__ wf2, const float* __restrict__ bf2,
    const float* __restrict__ ww1, const float* __restrict__ bw1,
    const float* __restrict__ ww2, const float* __restrict__ bw2,
    unsigned int* __restrict__ gates)
{
    const int tid = threadIdx.x;
    const int pos = blockIdx.x * 256 + tid;     // 0..65535
    const int t   = blockIdx.y;                 // 0..30
    const int b   = blockIdx.z;                 // 0..1
    const unsigned base = (unsigned)b * BS + (unsigned)t * TS + (unsigned)pos;

    f32x2 xv2[8];
#pragma unroll
    for (int q = 0; q < 8; ++q) {
        xv2[q].x = x[base + (unsigned)(2*q)   * CS];
        xv2[q].y = x[base + (unsigned)(2*q+1) * CS];
    }

    // conv1 (both branches) + tanh; weight pairs = wave-uniform global reads
    f32x2 af2[8], aw2[8];
#pragma unroll
    for (int o = 0; o < 16; ++o) {
        f32x2 a1 = {bf1[o], 0.f};
        f32x2 a2 = {bw1[o], 0.f};
#pragma unroll
        for (int q = 0; q < 8; ++q) {
            const f32x2 w1 = *(const f32x2*)&wf1[o * 16 + q * 2];
            const f32x2 w2 = *(const f32x2*)&ww1[o * 16 + q * 2];
            a1 = __builtin_elementwise_fma(w1, xv2[q], a1);
            a2 = __builtin_elementwise_fma(w2, xv2[q], a2);
        }
        const float va = ftanh(a1.x + a1.y);
        const float vw = ftanh(a2.x + a2.y);
        if (o & 1) { af2[o >> 1].y = va; aw2[o >> 1].y = vw; }
        else       { af2[o >> 1].x = va; aw2[o >> 1].x = vw; }
    }
    // conv2 (both branches) -> z=tanh, f=sigm -> manual pack -> store
#pragma unroll
    for (int o = 0; o < 16; ++o) {
        f32x2 a1 = {bf2[o], 0.f};
        f32x2 a2 = {bw2[o], 0.f};
#pragma unroll
        for (int q = 0; q < 8; ++q) {
            const f32x2 w1 = *(const f32x2*)&wf2[o * 16 + q * 2];
            const f32x2 w2 = *(const f32x2*)&ww2[o * 16 + q * 2];
            a1 = __builtin_elementwise_fma(w1, af2[q], a1);
            a2 = __builtin_elementwise_fma(w2, aw2[q], a2);
        }
        const float z = ftanh(a1.x + a1.y);
        const float f = fsigm(a2.x + a2.y);
        const int zi = (int)__builtin_rintf(z * 32767.0f);
        const unsigned fu = (unsigned)(f * 65535.0f + 0.5f);
        gates[base + (unsigned)o * CS] = ((unsigned)zi << 16) | (fu & 0xFFFFu);
    }
}

// ---------------- kB: scan over t (pure streaming) ----------------
// Thread = one (b, c, pos). 31 independent stride-TS gate loads (pipelined),
// register h-chain, h stored bf16 to ws (or f32 in-place over gates when ws
// is too small). Wave-level GAP partial per (b,c).
template<bool BF16H>
__global__ __launch_bounds__(256) void kB_scan(
    unsigned int* __restrict__ gates,       // also f32 h output when !BF16H
    unsigned short* __restrict__ hb,
    float* __restrict__ partials)
{
    const int pos = blockIdx.x * 256 + threadIdx.x;   // 0..65535
    const int c   = blockIdx.y;                       // 0..15
    const int b   = blockIdx.z;                       // 0..1
    const unsigned base = (unsigned)b * BS + (unsigned)c * CS + (unsigned)pos;

    float h = 0.f, s = 0.f;
#pragma unroll
    for (int t = 0; t < TDIM; ++t) {
        const unsigned wd = gates[base + (unsigned)t * TS];
        const float z = (float)((int)wd >> 16) * (1.0f / 32767.0f);
        const float f = (float)(wd & 0xFFFFu) * (1.0f / 65535.0f);
        h = fmaf(f, h - z, z);              // f*h + (1-f)*z
        s += h;
        if (BF16H) hb[base + (unsigned)t * TS] = (unsigned short)rhu16(h);
        else       ((float*)gates)[base + (unsigned)t * TS] = h;   // in-place
    }
#pragma unroll
    for (int off = 32; off; off >>= 1) s += __shfl_down(s, off, 64);
    const int lane = threadIdx.x & 63, wv = threadIdx.x >> 6;
    if (lane == 0)
        partials[(unsigned)(b * 16 + c) * 1024 + blockIdx.x * 4 + wv] = s;
}

// ---------------- k2: reduce partials -> att ----------------
__global__ __launch_bounds__(1024) void k2_attention(
    const float* __restrict__ partials, const float* __restrict__ wsca,
    const float* __restrict__ bsca, float* __restrict__ att)
{
    __shared__ float red[32][32];
    __shared__ float gap[32];
    const int tid = threadIdx.x;
    {
        const int bc = tid >> 5, seg = tid & 31;
        float s = 0.f;
        const float* p = partials + (unsigned)bc * 1024 + seg * 32;
#pragma unroll
        for (int j = 0; j < 32; ++j) s += p[j];
        red[bc][seg] = s;
    }
    __syncthreads();
    if (tid < 32) {
        float s = 0.f;
#pragma unroll
        for (int g = 0; g < 32; ++g) s += red[tid][g];
        gap[tid] = s * GAP_INV;
    }
    __syncthreads();
    if (tid < 32) {
        const int b = tid >> 4, o = tid & 15;
        float acc = bsca[o];
#pragma unroll
        for (int c = 0; c < 16; ++c) acc = fmaf(wsca[o*16 + c], gap[b*16 + c], acc);
        att[b*16 + o] = fsigm(acc);
    }
}

// ---------------- k3: scale ----------------
// bf16-h path: read h (bf16, ws), write fp32 out. grid (248, 32) x 1024: exact.
__global__ __launch_bounds__(1024) void k3_scale_b(
    const unsigned short* __restrict__ hb, const float* __restrict__ att,
    float* __restrict__ out)
{
    const int bc = blockIdx.y;
    const float a = att[bc];
    const unsigned i = blockIdx.x * 1024 + threadIdx.x;     // < 253,952 = CS/8
    const size_t base = (size_t)bc * CS;
    const ushort8v v = ((const ushort8v*)(hb + base))[i];
    float4 o1, o2;
    o1.x = bf2f(v[0])*a; o1.y = bf2f(v[1])*a; o1.z = bf2f(v[2])*a; o1.w = bf2f(v[3])*a;
    o2.x = bf2f(v[4])*a; o2.y = bf2f(v[5])*a; o2.z = bf2f(v[6])*a; o2.w = bf2f(v[7])*a;
    float4* op = (float4*)(out + base);
    op[i*2]     = o1;
    op[i*2 + 1] = o2;
}

// fallback: in-place fp32 scale (h already resides in d_out)
__global__ __launch_bounds__(1024) void k3_scale_a(
    const float* __restrict__ att, float* __restrict__ out)
{
    const int bc = blockIdx.y;
    const float a = att[bc];
    const unsigned i = blockIdx.x * 1024 + threadIdx.x;
    float4* op = (float4*)(out + (size_t)bc * CS);
    float4 v1 = op[i*2], v2 = op[i*2 + 1];
    v1.x *= a; v1.y *= a; v1.z *= a; v1.w *= a;
    v2.x *= a; v2.y *= a; v2.z *= a; v2.w *= a;
    op[i*2] = v1; op[i*2 + 1] = v2;
}

extern "C" void kernel_launch(void* const* d_in, const int* in_sizes, int n_in,
                              void* d_out, int out_size, void* d_ws, size_t ws_size,
                              hipStream_t stream) {
    const float* x    = (const float*)d_in[0];
    const float* wf1  = (const float*)d_in[1];
    const float* bf1  = (const float*)d_in[2];
    const float* wf2  = (const float*)d_in[3];
    const float* bf2  = (const float*)d_in[4];
    const float* ww1  = (const float*)d_in[5];
    const float* bw1  = (const float*)d_in[6];
    const float* ww2  = (const float*)d_in[7];
    const float* bw2  = (const float*)d_in[8];
    const float* wsca = (const float*)d_in[9];
    const float* bsca = (const float*)d_in[10];
    float* out = (float*)d_out;

    const size_t hbBytes   = (size_t)NTOT * 2;               // 130,023,424
    const size_t partBytes = (size_t)32 * 1024 * 4;          // 131,072
    const bool bf16h = ws_size >= hbBytes + partBytes + 256;

    // d_out doubles as the gate buffer (u32 per element = exactly out_size);
    // kB consumes gates (fallback: overwrites them with f32 h); k3 then fully
    // overwrites d_out with the final scaled output.
    unsigned int* gates = (unsigned int*)d_out;
    unsigned short* hb = (unsigned short*)d_ws;
    float* partials = bf16h ? (float*)((char*)d_ws + hbBytes) : (float*)d_ws;
    float* att = partials + 32 * 1024;

    kA_gates<<<dim3(256, TDIM, 2), 256, 0, stream>>>(
        x, wf1, bf1, wf2, bf2, ww1, bw1, ww2, bw2, gates);

    if (bf16h) {
        kB_scan<true><<<dim3(256, 16, 2), 256, 0, stream>>>(gates, hb, partials);
        k2_attention<<<1, 1024, 0, stream>>>(partials, wsca, bsca, att);
        k3_scale_b<<<dim3(248, 32), 1024, 0, stream>>>(hb, att, out);
    } else {
        kB_scan<false><<<dim3(256, 16, 2), 256, 0, stream>>>(gates, hb, partials);
        k2_attention<<<1, 1024, 0, stream>>>(partials, wsca, bsca, att);
        k3_scale_a<<<dim3(248, 32), 1024, 0, stream>>>(att, out);
    }
}

// Round 17
// 298.953 us; speedup vs baseline: 1.5939x; 1.0259x over previous
//
#include <hip/hip_runtime.h>
#include <hip/hip_bf16.h>

// x [B=2, C=16, T=31, H=256, W=256] fp32
#define TDIM 31
#define TS   65536                 // t stride (H*W)
#define CS   (TDIM * TS)           // c stride = 2,031,616
#define BS   (16 * CS)             // b stride
#define NTOT (2 * BS)              // 65,011,712
#define GAP_INV (1.0f / (31.0f * 65536.0f))

typedef __attribute__((ext_vector_type(8))) unsigned short ushort8v;
typedef float __attribute__((ext_vector_type(2))) f32x2;
typedef short __attribute__((ext_vector_type(2))) short2v;

__device__ __forceinline__ float frcp(float v){ return __builtin_amdgcn_rcpf(v); }
__device__ __forceinline__ float fexp2_(float v){ return __builtin_amdgcn_exp2f(v); }
__device__ __forceinline__ float ftanh(float x){ float e = fexp2_(x*2.8853900817779268f); return 1.0f - 2.0f*frcp(e+1.0f); }
__device__ __forceinline__ float fsigm(float x){ float e = fexp2_(x*-1.4426950408889634f); return frcp(1.0f+e); }
__device__ __forceinline__ unsigned rhu16(float x){ return (__float_as_uint(x) + 0x8000u) >> 16; }
__device__ __forceinline__ float bf2f(unsigned b){ return __uint_as_float(b << 16); }

// pack (snorm16(z) << 16) | snorm16(f) -- builtin (defined codegen; r10's
// inline-asm hazard was unaligned VOP3P pairs, not the instruction itself).
__device__ __forceinline__ unsigned packzf(float f, float z){
#if __has_builtin(__builtin_amdgcn_cvt_pknorm_i16)
    const short2v p = __builtin_amdgcn_cvt_pknorm_i16(f, z);   // lo=f, hi=z
    return __builtin_bit_cast(unsigned, p);
#else
    const int zi = (int)__builtin_rintf(z * 32767.0f);
    const int fi = (int)__builtin_rintf(f * 32767.0f);
    return ((unsigned)zi << 16) | ((unsigned)fi & 0xFFFFu);
#endif
}

// ---------------- kA: gates (pure streaming, t-parallel) ----------------
// r14: scalar FMA + SGPR weights, no LDS -> 201us @ 93% VALUBusy.
// r15: pk_fma (SGPR-pair weights)        -> 184us @ 75% VALUBusy.
// r16: pairwise-o loops (no conditional insert movs; 4 indep chains) and
// 1-instruction quantize via cvt_pknorm builtin. Both z,f snorm16.
// Thread = one (b, t, pos); writes packed gate u32 into gates (= d_out
// scratch; k3 overwrites d_out afterwards). 1 voxel/thread (r13 lesson);
// NO inline asm (r10 lesson); no launch_bounds min-waves (r6/r8 lesson).
__global__ __launch_bounds__(256) void kA_gates(
    const float* __restrict__ x,
    const float* __restrict__ wf1, const float* __restrict__ bf1,
    const float* __restrict__ wf2, const float* __restrict__ bf2,
    const float* __restrict__ ww1, const float* __restrict__ bw1,
    const float* __restrict__ ww2, const float* __restrict__ bw2,
    unsigned int* __restrict__ gates)
{
    const int tid = threadIdx.x;
    const int pos = blockIdx.x * 256 + tid;     // 0..65535
    const int t   = blockIdx.y;                 // 0..30
    const int b   = blockIdx.z;                 // 0..1
    const unsigned base = (unsigned)b * BS + (unsigned)t * TS + (unsigned)pos;

    f32x2 xv2[8];
#pragma unroll
    for (int q = 0; q < 8; ++q) {
        xv2[q].x = x[base + (unsigned)(2*q)   * CS];
        xv2[q].y = x[base + (unsigned)(2*q+1) * CS];
    }

    // conv1 (both branches, channels in pairs) + tanh
    f32x2 af2[8], aw2[8];
#pragma unroll
    for (int op = 0; op < 8; ++op) {
        const int o0 = 2 * op, o1 = 2 * op + 1;
        f32x2 a1e = {bf1[o0], 0.f}, a1o = {bf1[o1], 0.f};
        f32x2 a2e = {bw1[o0], 0.f}, a2o = {bw1[o1], 0.f};
#pragma unroll
        for (int q = 0; q < 8; ++q) {
            a1e = __builtin_elementwise_fma(*(const f32x2*)&wf1[o0*16 + q*2], xv2[q], a1e);
            a1o = __builtin_elementwise_fma(*(const f32x2*)&wf1[o1*16 + q*2], xv2[q], a1o);
            a2e = __builtin_elementwise_fma(*(const f32x2*)&ww1[o0*16 + q*2], xv2[q], a2e);
            a2o = __builtin_elementwise_fma(*(const f32x2*)&ww1[o1*16 + q*2], xv2[q], a2o);
        }
        af2[op].x = ftanh(a1e.x + a1e.y);
        af2[op].y = ftanh(a1o.x + a1o.y);
        aw2[op].x = ftanh(a2e.x + a2e.y);
        aw2[op].y = ftanh(a2o.x + a2o.y);
    }
    // conv2 (both branches, channels in pairs) -> z=tanh, f=sigm -> pack
#pragma unroll
    for (int op = 0; op < 8; ++op) {
        const int o0 = 2 * op, o1 = 2 * op + 1;
        f32x2 a1e = {bf2[o0], 0.f}, a1o = {bf2[o1], 0.f};
        f32x2 a2e = {bw2[o0], 0.f}, a2o = {bw2[o1], 0.f};
#pragma unroll
        for (int q = 0; q < 8; ++q) {
            a1e = __builtin_elementwise_fma(*(const f32x2*)&wf2[o0*16 + q*2], af2[q], a1e);
            a1o = __builtin_elementwise_fma(*(const f32x2*)&wf2[o1*16 + q*2], af2[q], a1o);
            a2e = __builtin_elementwise_fma(*(const f32x2*)&ww2[o0*16 + q*2], aw2[q], a2e);
            a2o = __builtin_elementwise_fma(*(const f32x2*)&ww2[o1*16 + q*2], aw2[q], a2o);
        }
        const float z0 = ftanh(a1e.x + a1e.y), z1 = ftanh(a1o.x + a1o.y);
        const float f0 = fsigm(a2e.x + a2e.y), f1 = fsigm(a2o.x + a2o.y);
        gates[base + (unsigned)o0 * CS] = packzf(f0, z0);
        gates[base + (unsigned)o1 * CS] = packzf(f1, z1);
    }
}

// ---------------- kB: scan over t (pure streaming) ----------------
// Thread = one (b, c, pos). 31 independent stride-TS gate loads (pipelined),
// register h-chain, h stored bf16 to ws (or f32 in-place over gates when ws
// is too small). Wave-level GAP partial per (b,c). Decode: z,f both snorm16.
template<bool BF16H>
__global__ __launch_bounds__(256) void kB_scan(
    unsigned int* __restrict__ gates,       // also f32 h output when !BF16H
    unsigned short* __restrict__ hb,
    float* __restrict__ partials)
{
    const int pos = blockIdx.x * 256 + threadIdx.x;   // 0..65535
    const int c   = blockIdx.y;                       // 0..15
    const int b   = blockIdx.z;                       // 0..1
    const unsigned base = (unsigned)b * BS + (unsigned)c * CS + (unsigned)pos;

    float h = 0.f, s = 0.f;
#pragma unroll
    for (int t = 0; t < TDIM; ++t) {
        const int wd = (int)gates[base + (unsigned)t * TS];
        const float z = (float)(wd >> 16) * (1.0f / 32767.0f);
        const float f = (float)((wd << 16) >> 16) * (1.0f / 32767.0f);
        h = fmaf(f, h - z, z);              // f*h + (1-f)*z
        s += h;
        if (BF16H) hb[base + (unsigned)t * TS] = (unsigned short)rhu16(h);
        else       ((float*)gates)[base + (unsigned)t * TS] = h;   // in-place
    }
#pragma unroll
    for (int off = 32; off; off >>= 1) s += __shfl_down(s, off, 64);
    const int lane = threadIdx.x & 63, wv = threadIdx.x >> 6;
    if (lane == 0)
        partials[(unsigned)(b * 16 + c) * 1024 + blockIdx.x * 4 + wv] = s;
}

// ---------------- k2: reduce partials -> att ----------------
__global__ __launch_bounds__(1024) void k2_attention(
    const float* __restrict__ partials, const float* __restrict__ wsca,
    const float* __restrict__ bsca, float* __restrict__ att)
{
    __shared__ float red[32][32];
    __shared__ float gap[32];
    const int tid = threadIdx.x;
    {
        const int bc = tid >> 5, seg = tid & 31;
        float s = 0.f;
        const float* p = partials + (unsigned)bc * 1024 + seg * 32;
#pragma unroll
        for (int j = 0; j < 32; ++j) s += p[j];
        red[bc][seg] = s;
    }
    __syncthreads();
    if (tid < 32) {
        float s = 0.f;
#pragma unroll
        for (int g = 0; g < 32; ++g) s += red[tid][g];
        gap[tid] = s * GAP_INV;
    }
    __syncthreads();
    if (tid < 32) {
        const int b = tid >> 4, o = tid & 15;
        float acc = bsca[o];
#pragma unroll
        for (int c = 0; c < 16; ++c) acc = fmaf(wsca[o*16 + c], gap[b*16 + c], acc);
        att[b*16 + o] = fsigm(acc);
    }
}

// ---------------- k3: scale ----------------
// bf16-h path: read h (bf16, ws), write fp32 out. grid (248, 32) x 1024: exact.
__global__ __launch_bounds__(1024) void k3_scale_b(
    const unsigned short* __restrict__ hb, const float* __restrict__ att,
    float* __restrict__ out)
{
    const int bc = blockIdx.y;
    const float a = att[bc];
    const unsigned i = blockIdx.x * 1024 + threadIdx.x;     // < 253,952 = CS/8
    const size_t base = (size_t)bc * CS;
    const ushort8v v = ((const ushort8v*)(hb + base))[i];
    float4 o1, o2;
    o1.x = bf2f(v[0])*a; o1.y = bf2f(v[1])*a; o1.z = bf2f(v[2])*a; o1.w = bf2f(v[3])*a;
    o2.x = bf2f(v[4])*a; o2.y = bf2f(v[5])*a; o2.z = bf2f(v[6])*a; o2.w = bf2f(v[7])*a;
    float4* op = (float4*)(out + base);
    op[i*2]     = o1;
    op[i*2 + 1] = o2;
}

// fallback: in-place fp32 scale (h already resides in d_out)
__global__ __launch_bounds__(1024) void k3_scale_a(
    const float* __restrict__ att, float* __restrict__ out)
{
    const int bc = blockIdx.y;
    const float a = att[bc];
    const unsigned i = blockIdx.x * 1024 + threadIdx.x;
    float4* op = (float4*)(out + (size_t)bc * CS);
    float4 v1 = op[i*2], v2 = op[i*2 + 1];
    v1.x *= a; v1.y *= a; v1.z *= a; v1.w *= a;
    v2.x *= a; v2.y *= a; v2.z *= a; v2.w *= a;
    op[i*2] = v1; op[i*2 + 1] = v2;
}

extern "C" void kernel_launch(void* const* d_in, const int* in_sizes, int n_in,
                              void* d_out, int out_size, void* d_ws, size_t ws_size,
                              hipStream_t stream) {
    const float* x    = (const float*)d_in[0];
    const float* wf1  = (const float*)d_in[1];
    const float* bf1  = (const float*)d_in[2];
    const float* wf2  = (const float*)d_in[3];
    const float* bf2  = (const float*)d_in[4];
    const float* ww1  = (const float*)d_in[5];
    const float* bw1  = (const float*)d_in[6];
    const float* ww2  = (const float*)d_in[7];
    const float* bw2  = (const float*)d_in[8];
    const float* wsca = (const float*)d_in[9];
    const float* bsca = (const float*)d_in[10];
    float* out = (float*)d_out;

    const size_t hbBytes   = (size_t)NTOT * 2;               // 130,023,424
    const size_t partBytes = (size_t)32 * 1024 * 4;          // 131,072
    const bool bf16h = ws_size >= hbBytes + partBytes + 256;

    // d_out doubles as the gate buffer (u32 per element = exactly out_size);
    // kB consumes gates (fallback: overwrites them with f32 h); k3 then fully
    // overwrites d_out with the final scaled output.
    unsigned int* gates = (unsigned int*)d_out;
    unsigned short* hb = (unsigned short*)d_ws;
    float* partials = bf16h ? (float*)((char*)d_ws + hbBytes) : (float*)d_ws;
    float* att = partials + 32 * 1024;

    kA_gates<<<dim3(256, TDIM, 2), 256, 0, stream>>>(
        x, wf1, bf1, wf2, bf2, ww1, bw1, ww2, bw2, gates);

    if (bf16h) {
        kB_scan<true><<<dim3(256, 16, 2), 256, 0, stream>>>(gates, hb, partials);
        k2_attention<<<1, 1024, 0, stream>>>(partials, wsca, bsca, att);
        k3_scale_b<<<dim3(248, 32), 1024, 0, stream>>>(hb, att, out);
    } else {
        kB_scan<false><<<dim3(256, 16, 2), 256, 0, stream>>>(gates, hb, partials);
        k2_attention<<<1, 1024, 0, stream>>>(partials, wsca, bsca, att);
        k3_scale_a<<<dim3(248, 32), 1024, 0, stream>>>(att, out);
    }
}